// Round 11
// baseline (65.943 us; speedup 1.0000x reference)
//
#include <hip/hip_runtime.h>
#include <stdint.h>

// DeformConv1d: x[8,256,4096] f32, offsets[8,1,4094,3] f32,
// weight[256,256,3] f32, bias[256] f32 -> out[8,256,4094] f32.
//
// R11 (on R10's A-through-LDS skeleton):
//  (a) M-split: 512 blocks (2/CU), each block 128 out-rows x 128 t.
//      mh pairs are bid-stride-8 -> same XCD -> shared x window in L2.
//  (b) As double-buffered + register prefetch -> ONE barrier per K-step.
//  (c) As rows padded to 40 shorts (80B, 16B-aligned) -> A-frag ds_read
//      bank spread (R10: 3.56M conflicts from 64B rows).
//  (d) x-window staging unrolled x4 -> 4-deep memory-level parallelism.
// Keeps: transposed swizzled Xt, register meta, rolled csub loop (I$),
// LDS epilogue (WRITE == output), XCD-chunked decode.

constexpr int CIN  = 256;
constexpr int LX   = 4096;
constexpr int KT   = 3;
constexpr int OUTL = 4094;
constexpr int COUT = 256;
constexpr int BN   = 128;    // t per block
constexpr int WPOS = 132;    // window positions staged (t0 .. t0+131)
constexpr int NQ   = 24;     // K-chunks of 32
constexpr int EPIW = 132;    // padded epilogue row (floats)
constexpr int APITCH = 40;   // padded A row (shorts) = 80B (16B-aligned)
constexpr int ABUF   = 128 * APITCH;  // 5120 shorts per buffer

typedef __attribute__((ext_vector_type(8))) short bf16x8;
typedef __attribute__((ext_vector_type(4))) float f32x4;

__device__ __forceinline__ short f2bf(float f) {        // round-half-up
  union { float f; uint32_t u; } v; v.f = f;
  return (short)((v.u + 0x8000u) >> 16);
}
__device__ __forceinline__ uint32_t pack_bf2(float flo, float fhi) {
  union { float f; uint32_t u; } a, b; a.f = flo; b.f = fhi;
  return ((a.u + 0x8000u) >> 16) | ((b.u + 0x8000u) & 0xFFFF0000u);
}
__device__ __forceinline__ float bf2f(short s) {
  union { uint32_t u; float f; } v;
  v.u = ((uint32_t)(uint16_t)s) << 16;
  return v.f;
}

// Apack[q][o][k'] with q = ch*12 + ktap*4 + csub,
// k' = 0..31 covering c = ch*128 + csub*32 + k'.  24*256*32 shorts = 384 KB.
__global__ __launch_bounds__(256) void pack_weights_kernel(
    const float* __restrict__ w, short* __restrict__ ap) {
  const int idx = blockIdx.x * 256 + threadIdx.x;   // one u32 = 2 shorts
  if (idx >= NQ * COUT * 32 / 2) return;
  const int s    = idx * 2;
  const int kp   = s & 31;
  const int o    = (s >> 5) & 255;
  const int q    = s >> 13;
  const int ch   = q / 12;
  const int ks   = q % 12;
  const int ktap = ks >> 2;
  const int c0   = ch * 128 + (ks & 3) * 32;
  const float f0 = w[((size_t)o * CIN + c0 + kp) * KT + ktap];
  const float f1 = w[((size_t)o * CIN + c0 + kp + 1) * KT + ktap];
  *(uint32_t*)&ap[s] = pack_bf2(f0, f1);
}

__global__ __launch_bounds__(512, 4) void deform_gemm_kernel(
    const float* __restrict__ x, const float* __restrict__ off,
    const short* __restrict__ ap, const float* __restrict__ bias,
    float* __restrict__ out) {

  // arena: [0,33792) Xt / Epi(reuse), [33792,54272) As[2], [54272,55296) bias
  __shared__ __align__(16) char smem[33792 + 2 * ABUF * 2 + 1024];
  short* Xt    = (short*)smem;
  short* As    = (short*)(smem + 33792);
  float* Epi   = (float*)smem;
  float* biasS = (float*)(smem + 33792 + 2 * ABUF * 2);

  const int tid  = threadIdx.x;
  const int lane = tid & 63;
  const int wid  = tid >> 6;       // 0..7
  const int llo  = lane & 15;
  const int lhi  = lane >> 4;

  // decode: b in low 3 bits (XCD-chunk); mh pairs at bid stride 8 (same XCD)
  const int b    = blockIdx.x & 7;        // 8 batches
  const int rest = blockIdx.x >> 3;       // 0..63
  const int mh   = rest & 1;              // M-half (rows mh*128 ..)
  const int tt   = rest >> 1;             // 32 t-tiles
  const int t0   = tt * BN;

  const int wm = (wid >> 2) * 64;   // 2 wave-rows in M (64 rows each)
  const int wn = (wid & 3) * 32;    // 4 wave-cols in N (32 t, 2 frags)

  // ---- per-lane interp meta in registers (statically indexed) ----
  float w0r[2][3], w1r[2][3];
  int   d0r[2][3];
  #pragma unroll
  for (int jn = 0; jn < 2; ++jn) {
    const int t = t0 + wn + jn * 16 + llo;
    #pragma unroll
    for (int k = 0; k < KT; ++k) {
      float w0 = 0.f, w1 = 0.f; int d0 = 0;
      if (t < OUTL) {
        const float o = off[((size_t)b * OUTL + t) * KT + k];
        float T = (float)(t + k) + o;
        T = fminf(fmaxf(T, (float)t), (float)(t + 2));  // clip to [t, t+2]
        int U0 = (int)T;                                 // floor (T >= 0)
        if (U0 > LX - 2) U0 = LX - 2;
        w1 = T - (float)U0;                              // in [0,1]
        w0 = 1.f - w1;
        d0 = U0 - t0;                                    // in [0, 130]
      }
      w0r[jn][k] = w0; w1r[jn][k] = w1; d0r[jn][k] = d0;
    }
  }
  if (tid < COUT) biasS[tid] = bias[tid];

  f32x4 acc[4][2];
  #pragma unroll
  for (int i = 0; i < 4; ++i) {
    acc[i][0] = (f32x4){0.f, 0.f, 0.f, 0.f};
    acc[i][1] = (f32x4){0.f, 0.f, 0.f, 0.f};
  }

  const float* xb = x + (size_t)b * CIN * LX;
  // per-thread A pointer: q advances by 8192 shorts; mh selects row half
  const short* apb = ap + mh * 4096 + tid * 8;
  bf16x8 aReg = *(const bf16x8*)apb;    // step 0 A data

  #pragma unroll 1
  for (int ch = 0; ch < 2; ++ch) {            // c-halves (ROLLED)
    // ---- stage x window half, transposed, 4-deep MLP ----
    // (entering ch=1: all waves passed step-11's barrier, so all Xt reads
    //  (B-build) are complete; staging may write without an extra barrier)
    #pragma unroll 1
    for (int g = 0; g < 8; ++g) {
      float fv[4]; int wi[4];
      #pragma unroll
      for (int j = 0; j < 4; ++j) {
        const int idx = (g * 4 + j) * 512 + tid;
        const int c   = idx / WPOS;
        const int pos = idx - c * WPOS;
        const int l   = t0 + pos;
        fv[j] = (l < LX) ? xb[(size_t)(ch * 128 + c) * LX + l] : 0.f;
        wi[j] = (pos * 128 + c) ^ ((pos & 7) << 3);
      }
      #pragma unroll
      for (int j = 0; j < 4; ++j) Xt[wi[j]] = f2bf(fv[j]);
    }
    {  // tail rep (32*512 .. 33*512): 33*512 == 128*WPOS exactly
      const int idx = 32 * 512 + tid;
      const int c   = idx / WPOS;
      const int pos = idx - c * WPOS;
      const int l   = t0 + pos;
      const float f = (l < LX) ? xb[(size_t)(ch * 128 + c) * LX + l] : 0.f;
      Xt[(pos * 128 + c) ^ ((pos & 7) << 3)] = f2bf(f);
    }
    __syncthreads();  // window (and bias on first pass) visible

    #pragma unroll
    for (int ktap = 0; ktap < KT; ++ktap) {   // UNROLLED: static meta index
      #pragma unroll 1
      for (int csub = 0; csub < 4; ++csub) {  // ROLLED: small I$ body
        const int sflat = ch * 12 + ktap * 4 + csub;
        short* asb = As + (sflat & 1) * ABUF;

        // ---- publish this step's A tile (loaded 1 step ago) ----
        // safe: readers of this buffer (step sflat-2) finished before
        // step sflat-1's barrier, which every wave has passed.
        *(bf16x8*)(asb + (tid >> 2) * APITCH + (tid & 3) * 8) = aReg;

        // ---- prefetch next step's A (clamped at the end; redundant ok) ----
        const int snx = sflat < NQ - 1 ? sflat + 1 : NQ - 1;
        aReg = *(const bf16x8*)(apb + (size_t)snx * 8192);

        // ---- B fragments from Xt (hides prefetch + write latency) ----
        bf16x8 bfr[2];
        #pragma unroll
        for (int jn = 0; jn < 2; ++jn) {
          const float w0 = w0r[jn][ktap];
          const float w1 = w1r[jn][ktap];
          const int   d0 = d0r[jn][ktap];
          const int   cb = csub * 32 + 8 * lhi;
          const int   i0 = (d0 * 128 + cb) ^ ((d0 & 7) << 3);
          const int   i1 = ((d0 + 1) * 128 + cb) ^ (((d0 + 1) & 7) << 3);
          const bf16x8 r0 = *(const bf16x8*)&Xt[i0];
          const bf16x8 r1 = *(const bf16x8*)&Xt[i1];
          #pragma unroll
          for (int j = 0; j < 8; ++j) {
            bfr[jn][j] = f2bf(bf2f(r0[j]) * w0 + bf2f(r1[j]) * w1);
          }
        }

        __syncthreads();   // As[buf] published, visible to all

        // ---- MFMA: 4 m-frags x 2 n-frags, A from LDS ----
        #pragma unroll
        for (int i = 0; i < 4; ++i) {
          const bf16x8 afr =
              *(const bf16x8*)(asb + (wm + i * 16 + llo) * APITCH + lhi * 8);
          acc[i][0] = __builtin_amdgcn_mfma_f32_16x16x32_bf16(afr, bfr[0], acc[i][0], 0, 0, 0);
          acc[i][1] = __builtin_amdgcn_mfma_f32_16x16x32_bf16(afr, bfr[1], acc[i][1], 0, 0, 0);
        }
      }
    }
  }

  // ---- epilogue: LDS-staged, contiguous row-segment stores ----
  // 4 passes of 32 rows (block-local rows 0..127; global = mh*128 + ...)
  const size_t obase = (size_t)b * COUT * OUTL + (size_t)mh * 128 * OUTL;
  #pragma unroll
  for (int p = 0; p < 4; ++p) {
    __syncthreads();   // p==0: Xt/As consumers done; else: prev consume done
    const int rbase = 32 * p;              // block-local row of this pass
    if (wm == (rbase & 64)) {              // 4 producer waves
      const int i0 = (rbase & 63) >> 4;    // {0,2,0,2}
      #pragma unroll
      for (int di = 0; di < 2; ++di) {
        const int i  = i0 + di;
        const int lr = 16 * di + 4 * lhi;  // local row in pass (plus r)
        #pragma unroll
        for (int jn = 0; jn < 2; ++jn) {
          const int col = wn + jn * 16 + llo;
          #pragma unroll
          for (int r = 0; r < 4; ++r) {
            Epi[(lr + r) * EPIW + col] =
                acc[i][jn][r] + biasS[mh * 128 + rbase + lr + r];
          }
        }
      }
    }
    __syncthreads();
    // consumer: 512 threads, 32 x 128 f32 tile; 32B per thread
    const int rr = tid >> 4;               // 0..31
    const int c8 = (tid & 15) * 8;         // 0..120
    float* op = out + obase + (size_t)(rbase + rr) * OUTL + t0 + c8;
    #pragma unroll
    for (int j2 = 0; j2 < 2; ++j2) {
      const f32x4 v = *(const f32x4*)&Epi[rr * EPIW + c8 + 4 * j2];
      const int   t = t0 + c8 + 4 * j2;
      if (t + 3 < OUTL) {
        *(f32x4*)(op + 4 * j2) = v;
      } else {
        #pragma unroll
        for (int e = 0; e < 4; ++e)
          if (t + e < OUTL) op[4 * j2 + e] = v[e];
      }
    }
  }
}

extern "C" void kernel_launch(void* const* d_in, const int* in_sizes, int n_in,
                              void* d_out, int out_size, void* d_ws, size_t ws_size,
                              hipStream_t stream) {
  const float* x    = (const float*)d_in[0];
  const float* off  = (const float*)d_in[1];
  const float* wgt  = (const float*)d_in[2];
  const float* bias = (const float*)d_in[3];
  float* out  = (float*)d_out;
  short* ap   = (short*)d_ws;   // 24*256*32*2 = 393216 B of scratch

  // pack weights (runs each call; deterministic, ~3 us)
  pack_weights_kernel<<<dim3((NQ * COUT * 32 / 2 + 255) / 256), dim3(256), 0, stream>>>(wgt, ap);
  // 8 b x 32 tt x 2 mh = 512 blocks (2/CU), 512 threads (8 waves)
  deform_gemm_kernel<<<dim3(512), dim3(512), 0, stream>>>(x, off, ap, bias, out);
}

// Round 12
// 51.932 us; speedup vs baseline: 1.2698x; 1.2698x over previous
//
#include <hip/hip_runtime.h>
#include <stdint.h>

// DeformConv1d: x[8,256,4096] f32, offsets[8,1,4094,3] f32,
// weight[256,256,3] f32, bias[256] f32 -> out[8,256,4094] f32.
//
// R12: R10's exact structure (A-through-LDS, 2-barrier K-step) with a
// t-split instead of R11's M-split: BN 128 -> 64, grid 256 -> 512
// (2 blocks/CU). Unlike the M-split this duplicates NO per-t work
// (B-build, x-window staging are split, not copied). Cross-block overlap
// hides the barrier-exposed A-latency that R10 (1 block/CU) serialized.
// Keeps: transposed swizzled Xt, register meta, rolled loops (I$),
// LDS epilogue (WRITE == output), XCD-chunked decode (th-pairs same XCD).

constexpr int CIN  = 256;
constexpr int LX   = 4096;
constexpr int KT   = 3;
constexpr int OUTL = 4094;
constexpr int COUT = 256;
constexpr int BN   = 64;    // t per block
constexpr int WPOS = 68;    // window positions staged (t0 .. t0+67)
constexpr int NQ   = 24;    // K-chunks of 32
constexpr int EPIW = 68;    // padded epilogue row (floats)

typedef __attribute__((ext_vector_type(8))) short bf16x8;
typedef __attribute__((ext_vector_type(4))) float f32x4;

__device__ __forceinline__ short f2bf(float f) {        // round-half-up
  union { float f; uint32_t u; } v; v.f = f;
  return (short)((v.u + 0x8000u) >> 16);
}
__device__ __forceinline__ uint32_t pack_bf2(float flo, float fhi) {
  union { float f; uint32_t u; } a, b; a.f = flo; b.f = fhi;
  return ((a.u + 0x8000u) >> 16) | ((b.u + 0x8000u) & 0xFFFF0000u);
}
__device__ __forceinline__ float bf2f(short s) {
  union { uint32_t u; float f; } v;
  v.u = ((uint32_t)(uint16_t)s) << 16;
  return v.f;
}

// Apack[q][o][k'] with q = ch*12 + ktap*4 + csub,
// k' = 0..31 covering c = ch*128 + csub*32 + k'.  24*256*32 shorts = 384 KB.
__global__ __launch_bounds__(256) void pack_weights_kernel(
    const float* __restrict__ w, short* __restrict__ ap) {
  const int idx = blockIdx.x * 256 + threadIdx.x;   // one u32 = 2 shorts
  if (idx >= NQ * COUT * 32 / 2) return;
  const int s    = idx * 2;
  const int kp   = s & 31;
  const int o    = (s >> 5) & 255;
  const int q    = s >> 13;
  const int ch   = q / 12;
  const int ks   = q % 12;
  const int ktap = ks >> 2;
  const int c0   = ch * 128 + (ks & 3) * 32;
  const float f0 = w[((size_t)o * CIN + c0 + kp) * KT + ktap];
  const float f1 = w[((size_t)o * CIN + c0 + kp + 1) * KT + ktap];
  *(uint32_t*)&ap[s] = pack_bf2(f0, f1);
}

__global__ __launch_bounds__(512, 4) void deform_gemm_kernel(
    const float* __restrict__ x, const float* __restrict__ off,
    const short* __restrict__ ap, const float* __restrict__ bias,
    float* __restrict__ out) {

  // arena: [0,17408) Xt / Epi(reuse), [17408,33792) As, [33792,34816) bias
  __shared__ __align__(16) char smem[17408 + 16384 + 1024];
  short* Xt    = (short*)smem;
  short* As    = (short*)(smem + 17408);
  float* Epi   = (float*)smem;         // needs 32*68*4 = 8704 B <= 17408
  float* biasS = (float*)(smem + 17408 + 16384);

  const int tid  = threadIdx.x;
  const int lane = tid & 63;
  const int wid  = tid >> 6;       // 0..7
  const int llo  = lane & 15;
  const int lhi  = lane >> 4;

  // decode: b in low 3 bits (XCD-chunk); th pairs at bid stride 8 (same XCD)
  const int b    = blockIdx.x & 7;        // 8 batches
  const int rest = blockIdx.x >> 3;       // 0..63
  const int th   = rest & 1;              // t-half
  const int tt   = rest >> 1;             // 32 coarse t-tiles
  const int t0   = tt * 128 + th * 64;

  const int wm = (wid >> 2) * 128;  // 2 wave-rows in M (128 rows each)
  const int wn = (wid & 3) * 16;    // 4 wave-cols in N (16 t each)

  // ---- per-lane interp meta in registers (statically indexed) ----
  float w0r[3], w1r[3];
  int   d0r[3];
  {
    const int t = t0 + wn + llo;
    #pragma unroll
    for (int k = 0; k < KT; ++k) {
      float w0 = 0.f, w1 = 0.f; int d0 = 0;
      if (t < OUTL) {
        const float o = off[((size_t)b * OUTL + t) * KT + k];
        float T = (float)(t + k) + o;
        T = fminf(fmaxf(T, (float)t), (float)(t + 2));  // clip to [t, t+2]
        int U0 = (int)T;                                 // floor (T >= 0)
        if (U0 > LX - 2) U0 = LX - 2;
        w1 = T - (float)U0;                              // in [0,1]
        w0 = 1.f - w1;
        d0 = U0 - t0;                                    // in [0, 66]
      }
      w0r[k] = w0; w1r[k] = w1; d0r[k] = d0;
    }
  }
  if (tid < COUT) biasS[tid] = bias[tid];

  f32x4 acc[8];
  #pragma unroll
  for (int i = 0; i < 8; ++i) acc[i] = (f32x4){0.f, 0.f, 0.f, 0.f};

  const float* xb = x + (size_t)b * CIN * LX;

  #pragma unroll 1
  for (int ch = 0; ch < 2; ++ch) {            // c-halves (ROLLED)
    if (ch) __syncthreads();                  // prev half's Xt consumers done
    // ---- stage x window half, transposed (ROLLED) ----
    // 128*68 = 8704 = 17 * 512 exactly.
    #pragma unroll 1
    for (int rep = 0; rep < 17; ++rep) {
      const int idx = rep * 512 + tid;
      const int c   = idx / WPOS;
      const int pos = idx - c * WPOS;
      const int l   = t0 + pos;
      const float f = (l < LX) ? xb[(size_t)(ch * 128 + c) * LX + l] : 0.f;
      const int wi  = (pos * 128 + c) ^ ((pos & 7) << 3);
      Xt[wi] = f2bf(f);
    }
    __syncthreads();  // window (and bias on first pass) visible

    #pragma unroll
    for (int ktap = 0; ktap < KT; ++ktap) {   // UNROLLED: static meta index
      #pragma unroll 1
      for (int csub = 0; csub < 4; ++csub) {  // ROLLED: small I$ body
        // ---- A stage: global (L2-hot packed) -> regs, issued FIRST ----
        const short* apq = ap + (((size_t)(ch * 12 + ktap * 4 + csub)) << 13);
        const bf16x8 a0 = *(const bf16x8*)(apq + tid * 8);
        const bf16x8 a1 = *(const bf16x8*)(apq + 4096 + tid * 8);

        // ---- B fragment from Xt (hides the A-load latency) ----
        bf16x8 bfr;
        {
          const float w0 = w0r[ktap];
          const float w1 = w1r[ktap];
          const int   d0 = d0r[ktap];
          const int   cb = csub * 32 + 8 * lhi;
          const int   i0 = (d0 * 128 + cb) ^ ((d0 & 7) << 3);
          const int   i1 = ((d0 + 1) * 128 + cb) ^ (((d0 + 1) & 7) << 3);
          const bf16x8 r0 = *(const bf16x8*)&Xt[i0];
          const bf16x8 r1 = *(const bf16x8*)&Xt[i1];
          #pragma unroll
          for (int j = 0; j < 8; ++j) {
            bfr[j] = f2bf(bf2f(r0[j]) * w0 + bf2f(r1[j]) * w1);
          }
        }

        // ---- A regs -> LDS (prev step's readers done: trailing barrier) ----
        *(bf16x8*)(As + tid * 8) = a0;
        *(bf16x8*)(As + 4096 + tid * 8) = a1;
        __syncthreads();   // As staged, visible to all

        // ---- MFMA: 8 m-frags x 1 n-frag, A from LDS ----
        #pragma unroll
        for (int i = 0; i < 8; ++i) {
          const bf16x8 afr = *(const bf16x8*)(As + (wm + i * 16 + llo) * 32 + lhi * 8);
          acc[i] = __builtin_amdgcn_mfma_f32_16x16x32_bf16(afr, bfr, acc[i], 0, 0, 0);
        }
        __syncthreads();   // all reads of As done before next stage
      }
    }
  }

  // ---- epilogue: LDS-staged, contiguous row-segment stores ----
  // 8 passes of 32 rows. (p-loop UNROLLED: static acc index — rule #20)
  const size_t obase = (size_t)b * COUT * OUTL;
  #pragma unroll
  for (int p = 0; p < 8; ++p) {
    __syncthreads();   // p==0: Xt/As consumers done; else: prev consume done
    const int rbase = 32 * p;              // absolute row of this pass
    if (wm == (rbase & 128)) {             // 4 producer waves
      const int i0 = (rbase & 127) >> 4;   // {0,2,4,6}
      #pragma unroll
      for (int di = 0; di < 2; ++di) {
        const int i  = i0 + di;
        const int lr = 16 * di + 4 * lhi;  // local row 0..31 (plus r)
        const int col = wn + llo;
        #pragma unroll
        for (int r = 0; r < 4; ++r) {
          Epi[(lr + r) * EPIW + col] = acc[i][r] + biasS[rbase + lr + r];
        }
      }
    }
    __syncthreads();
    // consumer: 512 threads, 32 x 64 f32 tile; 16B per thread
    const int rr = tid >> 4;               // 0..31
    const int c4 = (tid & 15) * 4;         // 0..60
    const f32x4 v = *(const f32x4*)&Epi[rr * EPIW + c4];
    const int   t = t0 + c4;
    float* op = out + obase + (size_t)(rbase + rr) * OUTL + t;
    if (t + 3 < OUTL) {
      *(f32x4*)op = v;
    } else {
      #pragma unroll
      for (int e = 0; e < 4; ++e)
        if (t + e < OUTL) op[e] = v[e];
    }
  }
}

extern "C" void kernel_launch(void* const* d_in, const int* in_sizes, int n_in,
                              void* d_out, int out_size, void* d_ws, size_t ws_size,
                              hipStream_t stream) {
  const float* x    = (const float*)d_in[0];
  const float* off  = (const float*)d_in[1];
  const float* wgt  = (const float*)d_in[2];
  const float* bias = (const float*)d_in[3];
  float* out  = (float*)d_out;
  short* ap   = (short*)d_ws;   // 24*256*32*2 = 393216 B of scratch

  // pack weights (runs each call; deterministic, ~3 us)
  pack_weights_kernel<<<dim3((NQ * COUT * 32 / 2 + 255) / 256), dim3(256), 0, stream>>>(wgt, ap);
  // 8 b x 32 tt x 2 th = 512 blocks (2/CU), 512 threads (8 waves)
  deform_gemm_kernel<<<dim3(512), dim3(512), 0, stream>>>(x, off, ap, bias, out);
}

// Round 13
// 51.398 us; speedup vs baseline: 1.2830x; 1.0104x over previous
//
#include <hip/hip_runtime.h>
#include <stdint.h>

// DeformConv1d: x[8,256,4096] f32, offsets[8,1,4094,3] f32,
// weight[256,256,3] f32, bias[256] f32 -> out[8,256,4094] f32.
//
// R13 = R12 (t-split, 2 blocks/CU, A-through-LDS) + the two fixes that
// R11 bundled with the bad M-split:
//  (a) As rows padded to 40 shorts (80B): A-frag ds_read bank starts
//      cycle all 8 groups (R12: 64B rows -> 8-way conflict, 5.3M cycles).
//  (b) As double-buffered + register prefetch -> ONE barrier per K-step
//      (publish step-s tile, prefetch s+1, B-build, barrier, MFMA).
// Keeps: transposed swizzled Xt, register meta, rolled loops (I$),
// LDS epilogue (WRITE == output), XCD-chunked decode.

constexpr int CIN  = 256;
constexpr int LX   = 4096;
constexpr int KT   = 3;
constexpr int OUTL = 4094;
constexpr int COUT = 256;
constexpr int BN   = 64;    // t per block
constexpr int WPOS = 68;    // window positions staged (t0 .. t0+67)
constexpr int NQ   = 24;    // K-chunks of 32
constexpr int EPIW = 68;    // padded epilogue row (floats)
constexpr int APITCH = 40;  // padded A row (shorts) = 80B, 16B-aligned
constexpr int ABUF   = 256 * APITCH;   // 10240 shorts per buffer

typedef __attribute__((ext_vector_type(8))) short bf16x8;
typedef __attribute__((ext_vector_type(4))) float f32x4;

__device__ __forceinline__ short f2bf(float f) {        // round-half-up
  union { float f; uint32_t u; } v; v.f = f;
  return (short)((v.u + 0x8000u) >> 16);
}
__device__ __forceinline__ uint32_t pack_bf2(float flo, float fhi) {
  union { float f; uint32_t u; } a, b; a.f = flo; b.f = fhi;
  return ((a.u + 0x8000u) >> 16) | ((b.u + 0x8000u) & 0xFFFF0000u);
}
__device__ __forceinline__ float bf2f(short s) {
  union { uint32_t u; float f; } v;
  v.u = ((uint32_t)(uint16_t)s) << 16;
  return v.f;
}

// Apack[q][o][k'] with q = ch*12 + ktap*4 + csub,
// k' = 0..31 covering c = ch*128 + csub*32 + k'.  24*256*32 shorts = 384 KB.
__global__ __launch_bounds__(256) void pack_weights_kernel(
    const float* __restrict__ w, short* __restrict__ ap) {
  const int idx = blockIdx.x * 256 + threadIdx.x;   // one u32 = 2 shorts
  if (idx >= NQ * COUT * 32 / 2) return;
  const int s    = idx * 2;
  const int kp   = s & 31;
  const int o    = (s >> 5) & 255;
  const int q    = s >> 13;
  const int ch   = q / 12;
  const int ks   = q % 12;
  const int ktap = ks >> 2;
  const int c0   = ch * 128 + (ks & 3) * 32;
  const float f0 = w[((size_t)o * CIN + c0 + kp) * KT + ktap];
  const float f1 = w[((size_t)o * CIN + c0 + kp + 1) * KT + ktap];
  *(uint32_t*)&ap[s] = pack_bf2(f0, f1);
}

__global__ __launch_bounds__(512, 4) void deform_gemm_kernel(
    const float* __restrict__ x, const float* __restrict__ off,
    const short* __restrict__ ap, const float* __restrict__ bias,
    float* __restrict__ out) {

  // arena: [0,17408) Xt / Epi(reuse), [17408,58368) As[2], [58368,59392) bias
  __shared__ __align__(16) char smem[17408 + 2 * ABUF * 2 + 1024];
  short* Xt    = (short*)smem;
  short* As    = (short*)(smem + 17408);
  float* Epi   = (float*)smem;         // needs 32*68*4 = 8704 B <= 17408
  float* biasS = (float*)(smem + 17408 + 2 * ABUF * 2);

  const int tid  = threadIdx.x;
  const int lane = tid & 63;
  const int wid  = tid >> 6;       // 0..7
  const int llo  = lane & 15;
  const int lhi  = lane >> 4;

  // decode: b in low 3 bits (XCD-chunk); th pairs at bid stride 8 (same XCD)
  const int b    = blockIdx.x & 7;        // 8 batches
  const int rest = blockIdx.x >> 3;       // 0..63
  const int th   = rest & 1;              // t-half
  const int tt   = rest >> 1;             // 32 coarse t-tiles
  const int t0   = tt * 128 + th * 64;

  const int wm = (wid >> 2) * 128;  // 2 wave-rows in M (128 rows each)
  const int wn = (wid & 3) * 16;    // 4 wave-cols in N (16 t each)

  // ---- per-lane interp meta in registers (statically indexed) ----
  float w0r[3], w1r[3];
  int   d0r[3];
  {
    const int t = t0 + wn + llo;
    #pragma unroll
    for (int k = 0; k < KT; ++k) {
      float w0 = 0.f, w1 = 0.f; int d0 = 0;
      if (t < OUTL) {
        const float o = off[((size_t)b * OUTL + t) * KT + k];
        float T = (float)(t + k) + o;
        T = fminf(fmaxf(T, (float)t), (float)(t + 2));  // clip to [t, t+2]
        int U0 = (int)T;                                 // floor (T >= 0)
        if (U0 > LX - 2) U0 = LX - 2;
        w1 = T - (float)U0;                              // in [0,1]
        w0 = 1.f - w1;
        d0 = U0 - t0;                                    // in [0, 66]
      }
      w0r[k] = w0; w1r[k] = w1; d0r[k] = d0;
    }
  }
  if (tid < COUT) biasS[tid] = bias[tid];

  f32x4 acc[8];
  #pragma unroll
  for (int i = 0; i < 8; ++i) acc[i] = (f32x4){0.f, 0.f, 0.f, 0.f};

  const float* xb = x + (size_t)b * CIN * LX;

  // register prefetch of step-0 A tile (each thread: rows tid>>2, 128+tid>>2)
  const short* apb = ap + tid * 8;
  bf16x8 aReg0 = *(const bf16x8*)apb;
  bf16x8 aReg1 = *(const bf16x8*)(apb + 4096);
  const int awr0 = (tid >> 2) * APITCH + (tid & 3) * 8;          // write offs
  const int awr1 = (128 + (tid >> 2)) * APITCH + (tid & 3) * 8;

  #pragma unroll 1
  for (int ch = 0; ch < 2; ++ch) {            // c-halves (ROLLED)
    if (ch) __syncthreads();                  // prev half's Xt consumers done
    // ---- stage x window half, transposed (ROLLED, unroll 2 for MLP) ----
    // 128*68 = 8704 = 17 * 512 exactly.
    #pragma unroll 2
    for (int rep = 0; rep < 17; ++rep) {
      const int idx = rep * 512 + tid;
      const int c   = idx / WPOS;
      const int pos = idx - c * WPOS;
      const int l   = t0 + pos;
      const float f = (l < LX) ? xb[(size_t)(ch * 128 + c) * LX + l] : 0.f;
      const int wi  = (pos * 128 + c) ^ ((pos & 7) << 3);
      Xt[wi] = f2bf(f);
    }
    __syncthreads();  // window (and bias on first pass) visible

    #pragma unroll
    for (int ktap = 0; ktap < KT; ++ktap) {   // UNROLLED: static meta index
      #pragma unroll 1
      for (int csub = 0; csub < 4; ++csub) {  // ROLLED: small I$ body
        const int sflat = ch * 12 + ktap * 4 + csub;
        short* asb = As + (sflat & 1) * ABUF;

        // ---- publish this step's A tile (loaded 1 step ago) ----
        // safe: readers of this buffer (step sflat-2) were lgkm-drained
        // at barrier(sflat-1), which every wave has passed.
        *(bf16x8*)(asb + awr0) = aReg0;
        *(bf16x8*)(asb + awr1) = aReg1;

        // ---- prefetch next step's A (clamped; redundant last load ok) ----
        const int snx = sflat < NQ - 1 ? sflat + 1 : NQ - 1;
        aReg0 = *(const bf16x8*)(apb + (size_t)snx * 8192);
        aReg1 = *(const bf16x8*)(apb + (size_t)snx * 8192 + 4096);

        // ---- B fragment from Xt (hides prefetch + write latency) ----
        bf16x8 bfr;
        {
          const float w0 = w0r[ktap];
          const float w1 = w1r[ktap];
          const int   d0 = d0r[ktap];
          const int   cb = csub * 32 + 8 * lhi;
          const int   i0 = (d0 * 128 + cb) ^ ((d0 & 7) << 3);
          const int   i1 = ((d0 + 1) * 128 + cb) ^ (((d0 + 1) & 7) << 3);
          const bf16x8 r0 = *(const bf16x8*)&Xt[i0];
          const bf16x8 r1 = *(const bf16x8*)&Xt[i1];
          #pragma unroll
          for (int j = 0; j < 8; ++j) {
            bfr[j] = f2bf(bf2f(r0[j]) * w0 + bf2f(r1[j]) * w1);
          }
        }

        __syncthreads();   // As[buf] published, visible to all

        // ---- MFMA: 8 m-frags x 1 n-frag, A from padded LDS ----
        #pragma unroll
        for (int i = 0; i < 8; ++i) {
          const bf16x8 afr =
              *(const bf16x8*)(asb + (wm + i * 16 + llo) * APITCH + lhi * 8);
          acc[i] = __builtin_amdgcn_mfma_f32_16x16x32_bf16(afr, bfr, acc[i], 0, 0, 0);
        }
      }
    }
  }

  // ---- epilogue: LDS-staged, contiguous row-segment stores ----
  // 8 passes of 32 rows. (p-loop UNROLLED: static acc index — rule #20)
  const size_t obase = (size_t)b * COUT * OUTL;
  #pragma unroll
  for (int p = 0; p < 8; ++p) {
    __syncthreads();   // p==0: Xt/As consumers drained; else: prev pass done
    const int rbase = 32 * p;              // absolute row of this pass
    if (wm == (rbase & 128)) {             // 4 producer waves
      const int i0 = (rbase & 127) >> 4;   // {0,2,4,6}
      #pragma unroll
      for (int di = 0; di < 2; ++di) {
        const int i  = i0 + di;
        const int lr = 16 * di + 4 * lhi;  // local row 0..31 (plus r)
        const int col = wn + llo;
        #pragma unroll
        for (int r = 0; r < 4; ++r) {
          Epi[(lr + r) * EPIW + col] = acc[i][r] + biasS[rbase + lr + r];
        }
      }
    }
    __syncthreads();
    // consumer: 512 threads, 32 x 64 f32 tile; 16B per thread
    const int rr = tid >> 4;               // 0..31
    const int c4 = (tid & 15) * 4;         // 0..60
    const f32x4 v = *(const f32x4*)&Epi[rr * EPIW + c4];
    const int   t = t0 + c4;
    float* op = out + obase + (size_t)(rbase + rr) * OUTL + t;
    if (t + 3 < OUTL) {
      *(f32x4*)op = v;
    } else {
      #pragma unroll
      for (int e = 0; e < 4; ++e)
        if (t + e < OUTL) op[e] = v[e];
    }
  }
}

extern "C" void kernel_launch(void* const* d_in, const int* in_sizes, int n_in,
                              void* d_out, int out_size, void* d_ws, size_t ws_size,
                              hipStream_t stream) {
  const float* x    = (const float*)d_in[0];
  const float* off  = (const float*)d_in[1];
  const float* wgt  = (const float*)d_in[2];
  const float* bias = (const float*)d_in[3];
  float* out  = (float*)d_out;
  short* ap   = (short*)d_ws;   // 24*256*32*2 = 393216 B of scratch

  // pack weights (runs each call; deterministic, ~3 us)
  pack_weights_kernel<<<dim3((NQ * COUT * 32 / 2 + 255) / 256), dim3(256), 0, stream>>>(wgt, ap);
  // 8 b x 32 tt x 2 th = 512 blocks (2/CU), 512 threads (8 waves)
  deform_gemm_kernel<<<dim3(512), dim3(512), 0, stream>>>(x, off, ap, bias, out);
}

// Round 14
// 48.086 us; speedup vs baseline: 1.3714x; 1.0689x over previous
//
#include <hip/hip_runtime.h>
#include <stdint.h>

// DeformConv1d: x[8,256,4096] f32, offsets[8,1,4094,3] f32,
// weight[256,256,3] f32, bias[256] f32 -> out[8,256,4094] f32.
//
// R14: LDS-port decongestion. R10-R13 plateau traced to ~55K cy/CU of
// LDS b128 issue (A-frag reads 4x redundant across waves). Changes:
//  - 32x32x16 MFMA, wave = 1 M-frag (32 rows) x 64 t: A-frags wave-private.
//  - A skips LDS entirely: packed d_ws layout gives each wave a coalesced
//    1KB global_load per K16-slice (L2-resident 384KB, prefetch 1 step).
//  - B precomputed per (ch,tap) into swizzled LDS tile Bp[t][c] (16KB):
//    interp VALU runs once, K-loop = barrier-free 4-step runs.
// Keeps (proven): transposed swizzled Xt window, interp math, register
// meta, LDS-staged epilogue, XCD-chunked decode, rolled loops.

constexpr int CIN  = 256;
constexpr int LX   = 4096;
constexpr int KT   = 3;
constexpr int OUTL = 4094;
constexpr int COUT = 256;
constexpr int BN   = 64;    // t per block
constexpr int WPOS = 68;    // window positions staged (t0 .. t0+67)
constexpr int NQ   = 24;    // K-chunks of 32
constexpr int EPIW = 68;    // padded epilogue row (floats)

typedef __attribute__((ext_vector_type(8))) short bf16x8;
typedef __attribute__((ext_vector_type(4))) float f32x4;
typedef __attribute__((ext_vector_type(16))) float f32x16;

__device__ __forceinline__ short f2bf(float f) {        // round-half-up
  union { float f; uint32_t u; } v; v.f = f;
  return (short)((v.u + 0x8000u) >> 16);
}
__device__ __forceinline__ float bf2f(short s) {
  union { uint32_t u; float f; } v;
  v.u = ((uint32_t)(uint16_t)s) << 16;
  return v.f;
}

// A pack: shorts idx = ((q*2+h)*8 + mf)*512 + l*8 + j
//   row = mf*32 + (l&31); c = ch*128 + (ks&3)*32 + h*16 + (l>>5)*8 + j;
//   tap = (q%12)>>2.  Wave mf's K16-slice (q,h) = ONE coalesced 1KB load.
__global__ __launch_bounds__(256) void pack_weights_kernel(
    const float* __restrict__ w, short* __restrict__ ap) {
  const int gid = blockIdx.x * 256 + threadIdx.x;
  if (gid >= NQ * 2 * 8 * 64) return;
  const int l   = gid & 63;
  const int mf  = (gid >> 6) & 7;
  const int h   = (gid >> 9) & 1;
  const int q   = gid >> 10;
  const int ch  = q / 12;
  const int ks  = q % 12;
  const int tap = ks >> 2;
  const int c0  = ch * 128 + (ks & 3) * 32 + h * 16 + (l >> 5) * 8;
  const int row = mf * 32 + (l & 31);
  bf16x8 v;
  #pragma unroll
  for (int j = 0; j < 8; ++j) {
    v[j] = f2bf(w[((size_t)row * CIN + c0 + j) * KT + tap]);
  }
  *(bf16x8*)(ap + (size_t)gid * 8) = v;
}

__global__ __launch_bounds__(512, 4) void deform_gemm_kernel(
    const float* __restrict__ x, const float* __restrict__ off,
    const short* __restrict__ ap, const float* __restrict__ bias,
    float* __restrict__ out) {

  // arena: [0,17408) Xt (shorts) / Epi (f32, epilogue reuse: 64x68x4),
  //        [17408,33792) Bp (shorts), [33792,34816) biasS
  __shared__ __align__(16) char smem[17408 + 16384 + 1024];
  short* Xt    = (short*)smem;
  short* Bp    = (short*)(smem + 17408);
  float* Epi   = (float*)smem;
  float* biasS = (float*)(smem + 17408 + 16384);

  const int tid  = threadIdx.x;
  const int lane = tid & 63;
  const int wid  = tid >> 6;       // 0..7 = M-frag index
  const int l31  = lane & 31;
  const int lh   = lane >> 5;      // k-half within fragment

  // decode: b in low 3 bits (XCD-chunk); th pairs at bid stride 8 (same XCD)
  const int b    = blockIdx.x & 7;        // 8 batches
  const int rest = blockIdx.x >> 3;       // 0..63
  const int th   = rest & 1;              // t-half
  const int tt   = rest >> 1;             // 32 coarse t-tiles
  const int t0   = tt * 128 + th * 64;

  // ---- per-thread interp meta for the Bp build (t = t0 + (tid&63)) ----
  float w0m[3], w1m[3];
  int   d0m[3];
  {
    const int t = t0 + (tid & 63);
    #pragma unroll
    for (int k = 0; k < KT; ++k) {
      float w0 = 0.f, w1 = 0.f; int d0 = 0;
      if (t < OUTL) {
        const float o = off[((size_t)b * OUTL + t) * KT + k];
        float T = (float)(t + k) + o;
        T = fminf(fmaxf(T, (float)t), (float)(t + 2));  // clip to [t, t+2]
        int U0 = (int)T;                                 // floor (T >= 0)
        if (U0 > LX - 2) U0 = LX - 2;
        w1 = T - (float)U0;                              // in [0,1]
        w0 = 1.f - w1;
        d0 = U0 - t0;                                    // in [0, 66]
      }
      w0m[k] = w0; w1m[k] = w1; d0m[k] = d0;
    }
  }
  if (tid < COUT) biasS[tid] = bias[tid];

  f32x16 acc0 = {0.f,0.f,0.f,0.f,0.f,0.f,0.f,0.f,0.f,0.f,0.f,0.f,0.f,0.f,0.f,0.f};
  f32x16 acc1 = {0.f,0.f,0.f,0.f,0.f,0.f,0.f,0.f,0.f,0.f,0.f,0.f,0.f,0.f,0.f,0.f};

  const float* xb = x + (size_t)b * CIN * LX;

  // A: wave-private coalesced loads; preload step 0 (both K16 halves)
  const short* apw = ap + wid * 512 + lane * 8;
  bf16x8 aC0 = *(const bf16x8*)apw;
  bf16x8 aC1 = *(const bf16x8*)(apw + 4096);

  #pragma unroll 1
  for (int ch = 0; ch < 2; ++ch) {            // c-halves (ROLLED)
    if (ch) __syncthreads();                  // drain prev half's Bp readers
    // ---- stage x window half, transposed (proven R12 block) ----
    // 128*68 = 8704 = 17 * 512 exactly.
    #pragma unroll 1
    for (int rep = 0; rep < 17; ++rep) {
      const int idx = rep * 512 + tid;
      const int c   = idx / WPOS;
      const int pos = idx - c * WPOS;
      const int l   = t0 + pos;
      const float f = (l < LX) ? xb[(size_t)(ch * 128 + c) * LX + l] : 0.f;
      const int wi  = (pos * 128 + c) ^ ((pos & 7) << 3);
      Xt[wi] = f2bf(f);
    }
    __syncthreads();  // window (and bias on first pass) visible

    #pragma unroll
    for (int tap = 0; tap < KT; ++tap) {      // UNROLLED: static meta index
      if (tap) __syncthreads();               // drain prev tap's Bp readers

      // ---- build Bp[t][c] (swizzled) for this (ch,tap): 64t x 128c ----
      // thread: t = tid&63, c-range = (tid>>6)*16 .. +15
      {
        const int tq = tid & 63;
        const int c0 = (tid >> 6) * 16;
        const float w0 = w0m[tap], w1 = w1m[tap];
        const int   d0 = d0m[tap];
        const int sw0 = (d0 & 7) << 3;
        const int sw1 = ((d0 + 1) & 7) << 3;
        const int r0i = d0 * 128, r1i = (d0 + 1) * 128;
        const bf16x8 r0a = *(const bf16x8*)&Xt[(r0i + c0)     ^ sw0];
        const bf16x8 r0b = *(const bf16x8*)&Xt[(r0i + c0 + 8) ^ sw0];
        const bf16x8 r1a = *(const bf16x8*)&Xt[(r1i + c0)     ^ sw1];
        const bf16x8 r1b = *(const bf16x8*)&Xt[(r1i + c0 + 8) ^ sw1];
        bf16x8 o1, o2;
        #pragma unroll
        for (int j = 0; j < 8; ++j) {
          o1[j] = f2bf(bf2f(r0a[j]) * w0 + bf2f(r1a[j]) * w1);
          o2[j] = f2bf(bf2f(r0b[j]) * w0 + bf2f(r1b[j]) * w1);
        }
        const int swt = (tq & 7) << 3;
        *(bf16x8*)&Bp[(tq * 128 + c0)     ^ swt] = o1;
        *(bf16x8*)&Bp[(tq * 128 + c0 + 8) ^ swt] = o2;
      }
      __syncthreads();  // Bp ready

      // ---- 4 barrier-free K-steps (K=32 each) ----
      #pragma unroll 1
      for (int csub = 0; csub < 4; ++csub) {
        const int q  = ch * 12 + tap * 4 + csub;
        const int qn = q < NQ - 1 ? q + 1 : NQ - 1;
        // prefetch next step's A (wave-private, L2-hot)
        const bf16x8 aN0 = *(const bf16x8*)(apw + (size_t)qn * 8192);
        const bf16x8 aN1 = *(const bf16x8*)(apw + (size_t)qn * 8192 + 4096);

        // B-frags: lane = col t' = jn*32+l31; elem j -> c-in-chunk h*16+lh*8+j
        const int cbase = csub * 32 + lh * 8;
        const int ta = l31,      swa = (ta & 7) << 3;  // jn = 0
        const int tb = 32 + l31, swb = (tb & 7) << 3;  // jn = 1
        const bf16x8 b00 = *(const bf16x8*)&Bp[(ta * 128 + cbase)      ^ swa];
        const bf16x8 b01 = *(const bf16x8*)&Bp[(ta * 128 + cbase + 16) ^ swa];
        const bf16x8 b10 = *(const bf16x8*)&Bp[(tb * 128 + cbase)      ^ swb];
        const bf16x8 b11 = *(const bf16x8*)&Bp[(tb * 128 + cbase + 16) ^ swb];

        acc0 = __builtin_amdgcn_mfma_f32_32x32x16_bf16(aC0, b00, acc0, 0, 0, 0);
        acc0 = __builtin_amdgcn_mfma_f32_32x32x16_bf16(aC1, b01, acc0, 0, 0, 0);
        acc1 = __builtin_amdgcn_mfma_f32_32x32x16_bf16(aC0, b10, acc1, 0, 0, 0);
        acc1 = __builtin_amdgcn_mfma_f32_32x32x16_bf16(aC1, b11, acc1, 0, 0, 0);

        aC0 = aN0; aC1 = aN1;
      }
    }
  }

  // ---- epilogue: LDS-staged, contiguous row-segment stores ----
  // 4 passes of 64 rows; producers = waves 2p, 2p+1 (their own M-frags).
  // 32x32 C/D layout: col = lane&31, row = (r&3) + 8*(r>>2) + 4*(lane>>5).
  const size_t obase = (size_t)b * COUT * OUTL;
  #pragma unroll
  for (int p = 0; p < 4; ++p) {
    __syncthreads();   // p==0: Xt->Epi reuse safe; else: prev consume done
    if ((wid >> 1) == p) {
      const int lrb = (wid & 1) * 32;
      #pragma unroll
      for (int r = 0; r < 16; ++r) {
        const int rowl = (r & 3) + 8 * (r >> 2) + 4 * lh;   // 0..31
        const int grow = p * 64 + lrb + rowl;               // == wid*32+rowl
        Epi[(lrb + rowl) * EPIW + l31]      = acc0[r] + biasS[grow];
        Epi[(lrb + rowl) * EPIW + 32 + l31] = acc1[r] + biasS[grow];
      }
    }
    __syncthreads();
    // consumer: 512 threads, 64 x 64 f32 tile; 32B per thread
    const int rr = tid >> 3;               // 0..63
    const int c8 = (tid & 7) * 8;          // 0..56
    float* op = out + obase + (size_t)(p * 64 + rr) * OUTL + t0 + c8;
    const f32x4 v0 = *(const f32x4*)&Epi[rr * EPIW + c8];
    const f32x4 v1 = *(const f32x4*)&Epi[rr * EPIW + c8 + 4];
    if (t0 + c8 + 7 < OUTL) {
      *(f32x4*)op = v0;
      *(f32x4*)(op + 4) = v1;
    } else {
      #pragma unroll
      for (int e = 0; e < 4; ++e) {
        if (t0 + c8 + e < OUTL)     op[e]     = v0[e];
        if (t0 + c8 + 4 + e < OUTL) op[4 + e] = v1[e];
      }
    }
  }
}

extern "C" void kernel_launch(void* const* d_in, const int* in_sizes, int n_in,
                              void* d_out, int out_size, void* d_ws, size_t ws_size,
                              hipStream_t stream) {
  const float* x    = (const float*)d_in[0];
  const float* off  = (const float*)d_in[1];
  const float* wgt  = (const float*)d_in[2];
  const float* bias = (const float*)d_in[3];
  float* out  = (float*)d_out;
  short* ap   = (short*)d_ws;   // 24*2*8*64*8 shorts = 393216 B of scratch

  // pack weights into wave-private coalesced A layout (~3 us)
  pack_weights_kernel<<<dim3(NQ * 2 * 8 * 64 / 256), dim3(256), 0, stream>>>(wgt, ap);
  // 8 b x 32 tt x 2 th = 512 blocks (2/CU), 512 threads (8 waves)
  deform_gemm_kernel<<<dim3(512), dim3(512), 0, stream>>>(x, off, ap, bias, out);
}

// Round 15
// 44.096 us; speedup vs baseline: 1.4955x; 1.0905x over previous
//
#include <hip/hip_runtime.h>
#include <stdint.h>

// DeformConv1d: x[8,256,4096] f32, offsets[8,1,4094,3] f32,
// weight[256,256,3] f32, bias[256] f32 -> out[8,256,4094] f32.
//
// R15 = R14 + async double-buffered x-window staging (T14):
//  - float4 staging loads, fully unrolled (5-deep MLP) instead of 17
//    serial 4B load->ds_write round-trips (the hidden serializer: HBM
//    duty cycle ~20%, all pipes idle).
//  - Xt double-buffered: ch1's loads ISSUE right after ch0's barrier and
//    stay in flight across ch0's whole Bp/GEMM phase; drained + written
//    at the ch boundary (one barrier).
// Unchanged from R14: 32x32x16 MFMA (wave-private A from L2, prefetch),
// Bp swizzled LDS tile, register meta, LDS epilogue, XCD decode.

constexpr int CIN  = 256;
constexpr int LX   = 4096;
constexpr int KT   = 3;
constexpr int OUTL = 4094;
constexpr int COUT = 256;
constexpr int WPOS = 68;    // window positions staged (t0 .. t0+67)
constexpr int NQ   = 24;    // K-chunks of 32
constexpr int EPIW = 68;    // padded epilogue row (floats)
constexpr int NIT  = 2176;  // 128 c * 17 float4-groups per half

typedef __attribute__((ext_vector_type(8))) short bf16x8;
typedef __attribute__((ext_vector_type(4))) float f32x4;
typedef __attribute__((ext_vector_type(16))) float f32x16;

__device__ __forceinline__ short f2bf(float f) {        // round-half-up
  union { float f; uint32_t u; } v; v.f = f;
  return (short)((v.u + 0x8000u) >> 16);
}
__device__ __forceinline__ float bf2f(short s) {
  union { uint32_t u; float f; } v;
  v.u = ((uint32_t)(uint16_t)s) << 16;
  return v.f;
}
__device__ __forceinline__ float4 loadx4(const float* p, int l) {
  if (l + 3 < LX) return *(const float4*)(p + l);   // l is 16B-aligned
  float4 v; v.x = v.y = v.z = v.w = 0.f;
  if (l + 0 < LX) v.x = p[l + 0];
  if (l + 1 < LX) v.y = p[l + 1];
  if (l + 2 < LX) v.z = p[l + 2];
  return v;  // l+3 >= LX in this branch
}

// A pack: shorts idx = ((q*2+h)*8 + mf)*512 + l*8 + j
//   row = mf*32 + (l&31); c = ch*128 + (ks&3)*32 + h*16 + (l>>5)*8 + j;
//   tap = (q%12)>>2.  Wave mf's K16-slice (q,h) = ONE coalesced 1KB load.
__global__ __launch_bounds__(256) void pack_weights_kernel(
    const float* __restrict__ w, short* __restrict__ ap) {
  const int gid = blockIdx.x * 256 + threadIdx.x;
  if (gid >= NQ * 2 * 8 * 64) return;
  const int l   = gid & 63;
  const int mf  = (gid >> 6) & 7;
  const int h   = (gid >> 9) & 1;
  const int q   = gid >> 10;
  const int ch  = q / 12;
  const int ks  = q % 12;
  const int tap = ks >> 2;
  const int c0  = ch * 128 + (ks & 3) * 32 + h * 16 + (l >> 5) * 8;
  const int row = mf * 32 + (l & 31);
  bf16x8 v;
  #pragma unroll
  for (int j = 0; j < 8; ++j) {
    v[j] = f2bf(w[((size_t)row * CIN + c0 + j) * KT + tap]);
  }
  *(bf16x8*)(ap + (size_t)gid * 8) = v;
}

__global__ __launch_bounds__(512, 4) void deform_gemm_kernel(
    const float* __restrict__ x, const float* __restrict__ off,
    const short* __restrict__ ap, const float* __restrict__ bias,
    float* __restrict__ out) {

  // arena: [0,17408) Xt0 / Epi(reuse), [17408,34816) Xt1,
  //        [34816,51200) Bp, [51200,52224) biasS
  __shared__ __align__(16) char smem[2 * 17408 + 16384 + 1024];
  short* Xt0   = (short*)smem;
  short* Xt1   = (short*)(smem + 17408);
  short* Bp    = (short*)(smem + 34816);
  float* Epi   = (float*)smem;
  float* biasS = (float*)(smem + 51200);

  const int tid  = threadIdx.x;
  const int lane = tid & 63;
  const int wid  = tid >> 6;       // 0..7 = M-frag index
  const int l31  = lane & 31;
  const int lh   = lane >> 5;      // k-half within fragment

  // decode: b in low 3 bits (XCD-chunk); th pairs at bid stride 8 (same XCD)
  const int b    = blockIdx.x & 7;        // 8 batches
  const int rest = blockIdx.x >> 3;       // 0..63
  const int th   = rest & 1;              // t-half
  const int tt   = rest >> 1;             // 32 coarse t-tiles
  const int t0   = tt * 128 + th * 64;

  // staging decode (shared by both halves): idx -> (c, g4)
  int xc[5], xg[5];
  #pragma unroll
  for (int r = 0; r < 5; ++r) {
    const int idx = r * 512 + tid;
    xc[r] = idx / 17;               // 0..127 (garbage for idx>=NIT, unused)
    xg[r] = idx - xc[r] * 17;       // 0..16
  }

  // ---- per-thread interp meta for the Bp build (t = t0 + (tid&63)) ----
  float w0m[3], w1m[3];
  int   d0m[3];
  {
    const int t = t0 + (tid & 63);
    #pragma unroll
    for (int k = 0; k < KT; ++k) {
      float w0 = 0.f, w1 = 0.f; int d0 = 0;
      if (t < OUTL) {
        const float o = off[((size_t)b * OUTL + t) * KT + k];
        float T = (float)(t + k) + o;
        T = fminf(fmaxf(T, (float)t), (float)(t + 2));  // clip to [t, t+2]
        int U0 = (int)T;                                 // floor (T >= 0)
        if (U0 > LX - 2) U0 = LX - 2;
        w1 = T - (float)U0;                              // in [0,1]
        w0 = 1.f - w1;
        d0 = U0 - t0;                                    // in [0, 66]
      }
      w0m[k] = w0; w1m[k] = w1; d0m[k] = d0;
    }
  }
  if (tid < COUT) biasS[tid] = bias[tid];

  f32x16 acc0 = {0.f,0.f,0.f,0.f,0.f,0.f,0.f,0.f,0.f,0.f,0.f,0.f,0.f,0.f,0.f,0.f};
  f32x16 acc1 = {0.f,0.f,0.f,0.f,0.f,0.f,0.f,0.f,0.f,0.f,0.f,0.f,0.f,0.f,0.f,0.f};

  const float* xb = x + (size_t)b * CIN * LX;

  // A: wave-private coalesced loads; preload step 0 (both K16 halves)
  const short* apw = ap + wid * 512 + lane * 8;
  bf16x8 aC0 = *(const bf16x8*)apw;
  bf16x8 aC1 = *(const bf16x8*)(apw + 4096);

  // ---- prologue: stage ch0 window (loads unrolled: 5-deep MLP) ----
  float4 xv[5];
  #pragma unroll
  for (int r = 0; r < 5; ++r)
    if (r * 512 + tid < NIT) xv[r] = loadx4(xb + (size_t)xc[r] * LX, t0 + 4 * xg[r]);
  #pragma unroll
  for (int r = 0; r < 5; ++r)
    if (r * 512 + tid < NIT) {
      const float fe[4] = {xv[r].x, xv[r].y, xv[r].z, xv[r].w};
      #pragma unroll
      for (int e = 0; e < 4; ++e) {
        const int pos = xg[r] * 4 + e;
        Xt0[(pos * 128 + xc[r]) ^ ((pos & 7) << 3)] = f2bf(fe[e]);
      }
    }
  __syncthreads();  // ch0 window (and bias) visible

  // ---- issue ch1 window loads NOW; they fly across ch0's compute ----
  #pragma unroll
  for (int r = 0; r < 5; ++r)
    if (r * 512 + tid < NIT)
      xv[r] = loadx4(xb + (size_t)(128 + xc[r]) * LX, t0 + 4 * xg[r]);

  #pragma unroll 1
  for (int ch = 0; ch < 2; ++ch) {            // c-halves (ROLLED)
    short* Xc = ch ? Xt1 : Xt0;

    #pragma unroll
    for (int tap = 0; tap < KT; ++tap) {      // UNROLLED: static meta index
      if (tap | ch) __syncthreads();          // drain prev Bp readers
                                              // (ch=1,tap=0: also Xt1 visible)
      // ---- build Bp[t][c] (swizzled) for this (ch,tap): 64t x 128c ----
      {
        const int tq = tid & 63;
        const int c0 = (tid >> 6) * 16;
        const float w0 = w0m[tap], w1 = w1m[tap];
        const int   d0 = d0m[tap];
        const int sw0 = (d0 & 7) << 3;
        const int sw1 = ((d0 + 1) & 7) << 3;
        const int r0i = d0 * 128, r1i = (d0 + 1) * 128;
        const bf16x8 r0a = *(const bf16x8*)&Xc[(r0i + c0)     ^ sw0];
        const bf16x8 r0b = *(const bf16x8*)&Xc[(r0i + c0 + 8) ^ sw0];
        const bf16x8 r1a = *(const bf16x8*)&Xc[(r1i + c0)     ^ sw1];
        const bf16x8 r1b = *(const bf16x8*)&Xc[(r1i + c0 + 8) ^ sw1];
        bf16x8 o1, o2;
        #pragma unroll
        for (int j = 0; j < 8; ++j) {
          o1[j] = f2bf(bf2f(r0a[j]) * w0 + bf2f(r1a[j]) * w1);
          o2[j] = f2bf(bf2f(r0b[j]) * w0 + bf2f(r1b[j]) * w1);
        }
        const int swt = (tq & 7) << 3;
        *(bf16x8*)&Bp[(tq * 128 + c0)     ^ swt] = o1;
        *(bf16x8*)&Bp[(tq * 128 + c0 + 8) ^ swt] = o2;
      }
      __syncthreads();  // Bp ready

      // ---- 4 barrier-free K-steps (K=32 each) ----
      #pragma unroll 1
      for (int csub = 0; csub < 4; ++csub) {
        const int q  = ch * 12 + tap * 4 + csub;
        const int qn = q < NQ - 1 ? q + 1 : NQ - 1;
        // prefetch next step's A (wave-private, L2-hot)
        const bf16x8 aN0 = *(const bf16x8*)(apw + (size_t)qn * 8192);
        const bf16x8 aN1 = *(const bf16x8*)(apw + (size_t)qn * 8192 + 4096);

        // B-frags: lane = col t' = jn*32+l31; elem j -> c-in-chunk h*16+lh*8+j
        const int cbase = csub * 32 + lh * 8;
        const int ta = l31,      swa = (ta & 7) << 3;  // jn = 0
        const int tb = 32 + l31, swb = (tb & 7) << 3;  // jn = 1
        const bf16x8 b00 = *(const bf16x8*)&Bp[(ta * 128 + cbase)      ^ swa];
        const bf16x8 b01 = *(const bf16x8*)&Bp[(ta * 128 + cbase + 16) ^ swa];
        const bf16x8 b10 = *(const bf16x8*)&Bp[(tb * 128 + cbase)      ^ swb];
        const bf16x8 b11 = *(const bf16x8*)&Bp[(tb * 128 + cbase + 16) ^ swb];

        acc0 = __builtin_amdgcn_mfma_f32_32x32x16_bf16(aC0, b00, acc0, 0, 0, 0);
        acc0 = __builtin_amdgcn_mfma_f32_32x32x16_bf16(aC1, b01, acc0, 0, 0, 0);
        acc1 = __builtin_amdgcn_mfma_f32_32x32x16_bf16(aC0, b10, acc1, 0, 0, 0);
        acc1 = __builtin_amdgcn_mfma_f32_32x32x16_bf16(aC1, b11, acc1, 0, 0, 0);

        aC0 = aN0; aC1 = aN1;
      }
    }

    // ---- ch boundary: drain the in-flight ch1 loads, publish window ----
    if (ch == 0) {
      #pragma unroll
      for (int r = 0; r < 5; ++r)
        if (r * 512 + tid < NIT) {
          const float fe[4] = {xv[r].x, xv[r].y, xv[r].z, xv[r].w};
          #pragma unroll
          for (int e = 0; e < 4; ++e) {
            const int pos = xg[r] * 4 + e;
            Xt1[(pos * 128 + xc[r]) ^ ((pos & 7) << 3)] = f2bf(fe[e]);
          }
        }
      // visibility handled by the (tap|ch) barrier at ch=1, tap=0
    }
  }

  // ---- epilogue: LDS-staged, contiguous row-segment stores ----
  // 4 passes of 64 rows; producers = waves 2p, 2p+1 (their own M-frags).
  // 32x32 C/D layout: col = lane&31, row = (r&3) + 8*(r>>2) + 4*(lane>>5).
  const size_t obase = (size_t)b * COUT * OUTL;
  #pragma unroll
  for (int p = 0; p < 4; ++p) {
    __syncthreads();   // p==0: Xt0->Epi reuse safe; else: prev consume done
    if ((wid >> 1) == p) {
      const int lrb = (wid & 1) * 32;
      #pragma unroll
      for (int r = 0; r < 16; ++r) {
        const int rowl = (r & 3) + 8 * (r >> 2) + 4 * lh;   // 0..31
        const int grow = p * 64 + lrb + rowl;               // == wid*32+rowl
        Epi[(lrb + rowl) * EPIW + l31]      = acc0[r] + biasS[grow];
        Epi[(lrb + rowl) * EPIW + 32 + l31] = acc1[r] + biasS[grow];
      }
    }
    __syncthreads();
    // consumer: 512 threads, 64 x 64 f32 tile; 32B per thread
    const int rr = tid >> 3;               // 0..63
    const int c8 = (tid & 7) * 8;          // 0..56
    float* op = out + obase + (size_t)(p * 64 + rr) * OUTL + t0 + c8;
    const f32x4 v0 = *(const f32x4*)&Epi[rr * EPIW + c8];
    const f32x4 v1 = *(const f32x4*)&Epi[rr * EPIW + c8 + 4];
    if (t0 + c8 + 7 < OUTL) {
      *(f32x4*)op = v0;
      *(f32x4*)(op + 4) = v1;
    } else {
      #pragma unroll
      for (int e = 0; e < 4; ++e) {
        if (t0 + c8 + e < OUTL)     op[e]     = v0[e];
        if (t0 + c8 + 4 + e < OUTL) op[4 + e] = v1[e];
      }
    }
  }
}

extern "C" void kernel_launch(void* const* d_in, const int* in_sizes, int n_in,
                              void* d_out, int out_size, void* d_ws, size_t ws_size,
                              hipStream_t stream) {
  const float* x    = (const float*)d_in[0];
  const float* off  = (const float*)d_in[1];
  const float* wgt  = (const float*)d_in[2];
  const float* bias = (const float*)d_in[3];
  float* out  = (float*)d_out;
  short* ap   = (short*)d_ws;   // 24*2*8*64*8 shorts = 393216 B of scratch

  // pack weights into wave-private coalesced A layout (~3 us)
  pack_weights_kernel<<<dim3(NQ * 2 * 8 * 64 / 256), dim3(256), 0, stream>>>(wgt, ap);
  // 8 b x 32 tt x 2 th = 512 blocks (2/CU), 512 threads (8 waves)
  deform_gemm_kernel<<<dim3(512), dim3(512), 0, stream>>>(x, off, ap, bias, out);
}